// Round 1
// baseline (467.666 us; speedup 1.0000x reference)
//
#include <hip/hip_runtime.h>

#define N_TOK 2048
#define DMODEL 1024
#define NEXP 8
#define FFDIM 4096
#define NMAX 2048

#define BM 128
#define BN 128
#define BK 64
#define LDT 72  // 64 + 8 pad: row stride 144B = 36 banks ≡ 4 mod 32 → 2-way (free)

typedef __attribute__((ext_vector_type(8))) short s16x8;
typedef __attribute__((ext_vector_type(4))) float f32x4;

__device__ __forceinline__ float bf2f(ushort u) {
    union { uint i; float f; } x; x.i = ((uint)u) << 16; return x.f;
}
__device__ __forceinline__ ushort f2bf(float f) {
    union { float f; uint i; } x; x.f = f;
    uint r = x.i + 0x7fffu + ((x.i >> 16) & 1u);
    return (ushort)(r >> 16);
}

__device__ __forceinline__ float block_sum(float v, float* s4) {
    #pragma unroll
    for (int off = 32; off; off >>= 1) v += __shfl_down(v, off);
    __syncthreads();
    if ((threadIdx.x & 63) == 0) s4[threadIdx.x >> 6] = v;
    __syncthreads();
    return s4[0] + s4[1] + s4[2] + s4[3];
}

// ---------------- Router: LN stats, norm->bf16, logits, softmax, top-2 ----------------
__global__ __launch_bounds__(256)
void router_kernel(const float* __restrict__ x, const float* __restrict__ gate_w,
                   ushort* __restrict__ norm, float* __restrict__ scores,
                   int* __restrict__ cnt, int* __restrict__ lists, float* __restrict__ gates) {
    __shared__ float s4[4];
    const int n = blockIdx.x, tid = threadIdx.x;
    const float* xr = x + (size_t)n * DMODEL;
    float4 v = *(const float4*)(xr + tid * 4);

    float tot = block_sum(v.x + v.y + v.z + v.w, s4);
    float mu = tot * (1.0f / DMODEL);
    float d0 = v.x - mu, d1 = v.y - mu, d2 = v.z - mu, d3 = v.w - mu;
    float var = block_sum(d0 * d0 + d1 * d1 + d2 * d2 + d3 * d3, s4) * (1.0f / DMODEL);
    float rstd = rsqrtf(var + 1e-6f);

    ushort nb[4] = { f2bf(d0 * rstd), f2bf(d1 * rstd), f2bf(d2 * rstd), f2bf(d3 * rstd) };
    *(uint2*)(norm + (size_t)n * DMODEL + tid * 4) = *(uint2*)nb;

    float lg[NEXP];
    #pragma unroll
    for (int e = 0; e < NEXP; ++e) {
        float4 g = *(const float4*)(gate_w + (size_t)e * DMODEL + tid * 4);
        lg[e] = v.x * g.x + v.y * g.y + v.z * g.z + v.w * g.w;
    }
    #pragma unroll
    for (int e = 0; e < NEXP; ++e) lg[e] = block_sum(lg[e], s4);

    if (tid == 0) {
        float m = lg[0];
        #pragma unroll
        for (int e = 1; e < NEXP; ++e) m = fmaxf(m, lg[e]);
        float ex[NEXP], Z = 0.f;
        #pragma unroll
        for (int e = 0; e < NEXP; ++e) { ex[e] = expf(lg[e] - m); Z += ex[e]; }
        float inv = 1.0f / Z;
        float sc[NEXP];
        #pragma unroll
        for (int e = 0; e < NEXP; ++e) { sc[e] = ex[e] * inv; scores[n * NEXP + e] = sc[e]; }
        int i1 = 0;
        #pragma unroll
        for (int e = 1; e < NEXP; ++e) if (sc[e] > sc[i1]) i1 = e;
        int i2 = (i1 == 0) ? 1 : 0;
        #pragma unroll
        for (int e = 0; e < NEXP; ++e) if (e != i1 && sc[e] > sc[i2]) i2 = e;
        int s1 = atomicAdd(&cnt[i1], 1);
        lists[i1 * NMAX + s1] = n; gates[i1 * NMAX + s1] = sc[i1];
        int s2 = atomicAdd(&cnt[i2], 1);
        lists[i2 * NMAX + s2] = n; gates[i2 * NMAX + s2] = sc[i2];
    }
}

// ---------------- Prep: aux loss + exclusive scan of counts ----------------
__global__ __launch_bounds__(256)
void prep_kernel(const float* __restrict__ scores, const int* __restrict__ cnt,
                 int* __restrict__ offs, float* __restrict__ aux_out) {
    __shared__ float s4[4];
    __shared__ float imp[NEXP];
    float part[NEXP] = {};
    for (int i = threadIdx.x; i < N_TOK; i += 256) {
        #pragma unroll
        for (int e = 0; e < NEXP; ++e) part[e] += scores[i * NEXP + e];
    }
    #pragma unroll
    for (int e = 0; e < NEXP; ++e) {
        float s = block_sum(part[e], s4);
        if (threadIdx.x == 0) imp[e] = s;
    }
    __syncthreads();
    if (threadIdx.x == 0) {
        float aux = 0.f; int run = 0;
        #pragma unroll
        for (int e = 0; e < NEXP; ++e) {
            aux += imp[e] * (float)cnt[e];
            offs[e] = run; run += cnt[e];
        }
        aux_out[0] = aux * (float)NEXP / ((float)N_TOK * (float)N_TOK);
    }
}

// ---------------- GEMM1: h = relu((norm*g+b) @ w1^T + b1), per expert ----------------
__global__ __launch_bounds__(256)
void gemm1_kernel(const ushort* __restrict__ norm, const float* __restrict__ w1,
                  const float* __restrict__ b1, const float* __restrict__ ln_g,
                  const float* __restrict__ ln_b, const int* __restrict__ cnt,
                  const int* __restrict__ offs, const int* __restrict__ lists,
                  ushort* __restrict__ h) {
    const int e = blockIdx.z, mt = blockIdx.y, nt = blockIdx.x;
    const int M = cnt[e];
    if (mt * BM >= M) return;
    const int base = offs[e];

    __shared__ ushort As[BM][LDT];
    __shared__ ushort Ws[BN][LDT];
    const int tid = threadIdx.x;
    const int lane = tid & 63, wave = tid >> 6;
    const int wm = (wave & 1) * 64, wn = (wave >> 1) * 64;

    f32x4 acc[4][4] = {};

    for (int kt = 0; kt < DMODEL / BK; ++kt) {
        __syncthreads();
        #pragma unroll
        for (int ci = 0; ci < 4; ++ci) {
            int c = tid + 256 * ci;
            int row = c >> 3, col8 = (c & 7) * 8;
            int kg = kt * BK + col8;
            // A: gathered token rows, with per-expert LN affine
            int slot = mt * BM + row;
            ushort ob[8] = {};
            if (slot < M) {
                int token = lists[e * NMAX + slot];
                uint4 u = *(const uint4*)(norm + (size_t)token * DMODEL + kg);
                ushort us[8]; *(uint4*)us = u;
                float4 g0 = *(const float4*)(ln_g + (size_t)e * DMODEL + kg);
                float4 g1 = *(const float4*)(ln_g + (size_t)e * DMODEL + kg + 4);
                float4 bb0 = *(const float4*)(ln_b + (size_t)e * DMODEL + kg);
                float4 bb1 = *(const float4*)(ln_b + (size_t)e * DMODEL + kg + 4);
                float gv[8] = { g0.x, g0.y, g0.z, g0.w, g1.x, g1.y, g1.z, g1.w };
                float bv[8] = { bb0.x, bb0.y, bb0.z, bb0.w, bb1.x, bb1.y, bb1.z, bb1.w };
                #pragma unroll
                for (int j = 0; j < 8; ++j) ob[j] = f2bf(bf2f(us[j]) * gv[j] + bv[j]);
            }
            *(s16x8*)&As[row][col8] = *(s16x8*)ob;
            // W: w1[e][nrow][k] f32 -> bf16
            const float* wp = w1 + ((size_t)e * FFDIM + nt * BN + row) * DMODEL + kg;
            float4 wa = *(const float4*)wp;
            float4 wb = *(const float4*)(wp + 4);
            ushort wo[8] = { f2bf(wa.x), f2bf(wa.y), f2bf(wa.z), f2bf(wa.w),
                             f2bf(wb.x), f2bf(wb.y), f2bf(wb.z), f2bf(wb.w) };
            *(s16x8*)&Ws[row][col8] = *(s16x8*)wo;
        }
        __syncthreads();
        #pragma unroll
        for (int kk = 0; kk < BK; kk += 32) {
            s16x8 af[4], bfr[4];
            #pragma unroll
            for (int mi = 0; mi < 4; ++mi)
                af[mi] = *(const s16x8*)&As[wm + mi * 16 + (lane & 15)][kk + (lane >> 4) * 8];
            #pragma unroll
            for (int ni = 0; ni < 4; ++ni)
                bfr[ni] = *(const s16x8*)&Ws[wn + ni * 16 + (lane & 15)][kk + (lane >> 4) * 8];
            #pragma unroll
            for (int mi = 0; mi < 4; ++mi)
                #pragma unroll
                for (int ni = 0; ni < 4; ++ni)
                    acc[mi][ni] = __builtin_amdgcn_mfma_f32_16x16x32_bf16(af[mi], bfr[ni], acc[mi][ni], 0, 0, 0);
        }
    }
    #pragma unroll
    for (int mi = 0; mi < 4; ++mi)
        #pragma unroll
        for (int r = 0; r < 4; ++r) {
            int m = wm + mi * 16 + ((lane >> 4) << 2) + r;
            int slot = mt * BM + m;
            if (slot < M) {
                #pragma unroll
                for (int ni = 0; ni < 4; ++ni) {
                    int nn = nt * BN + wn + ni * 16 + (lane & 15);
                    float v = acc[mi][ni][r] + b1[(size_t)e * FFDIM + nn];
                    h[(size_t)(base + slot) * FFDIM + nn] = f2bf(fmaxf(v, 0.f));
                }
            }
        }
}

// ---------------- GEMM2: y = h @ w2^T; out += g*(y + b2 + x_skip) ----------------
__global__ __launch_bounds__(256)
void gemm2_kernel(const ushort* __restrict__ h, const float* __restrict__ w2,
                  const float* __restrict__ b2, const float* __restrict__ x,
                  const int* __restrict__ cnt, const int* __restrict__ offs,
                  const int* __restrict__ lists, const float* __restrict__ gates,
                  float* __restrict__ out) {
    const int e = blockIdx.z, mt = blockIdx.y, nt = blockIdx.x;
    const int M = cnt[e];
    if (mt * BM >= M) return;
    const int base = offs[e];

    __shared__ ushort As[BM][LDT];
    __shared__ ushort Ws[BN][LDT];
    const int tid = threadIdx.x;
    const int lane = tid & 63, wave = tid >> 6;
    const int wm = (wave & 1) * 64, wn = (wave >> 1) * 64;

    f32x4 acc[4][4] = {};

    for (int kt = 0; kt < FFDIM / BK; ++kt) {
        __syncthreads();
        #pragma unroll
        for (int ci = 0; ci < 4; ++ci) {
            int c = tid + 256 * ci;
            int row = c >> 3, col8 = (c & 7) * 8;
            int kg = kt * BK + col8;
            int slot = mt * BM + row;
            s16x8 av = {};
            if (slot < M)
                av = *(const s16x8*)(h + (size_t)(base + slot) * FFDIM + kg);
            *(s16x8*)&As[row][col8] = av;
            const float* wp = w2 + ((size_t)e * DMODEL + nt * BN + row) * FFDIM + kg;
            float4 wa = *(const float4*)wp;
            float4 wb = *(const float4*)(wp + 4);
            ushort wo[8] = { f2bf(wa.x), f2bf(wa.y), f2bf(wa.z), f2bf(wa.w),
                             f2bf(wb.x), f2bf(wb.y), f2bf(wb.z), f2bf(wb.w) };
            *(s16x8*)&Ws[row][col8] = *(s16x8*)wo;
        }
        __syncthreads();
        #pragma unroll
        for (int kk = 0; kk < BK; kk += 32) {
            s16x8 af[4], bfr[4];
            #pragma unroll
            for (int mi = 0; mi < 4; ++mi)
                af[mi] = *(const s16x8*)&As[wm + mi * 16 + (lane & 15)][kk + (lane >> 4) * 8];
            #pragma unroll
            for (int ni = 0; ni < 4; ++ni)
                bfr[ni] = *(const s16x8*)&Ws[wn + ni * 16 + (lane & 15)][kk + (lane >> 4) * 8];
            #pragma unroll
            for (int mi = 0; mi < 4; ++mi)
                #pragma unroll
                for (int ni = 0; ni < 4; ++ni)
                    acc[mi][ni] = __builtin_amdgcn_mfma_f32_16x16x32_bf16(af[mi], bfr[ni], acc[mi][ni], 0, 0, 0);
        }
    }
    #pragma unroll
    for (int mi = 0; mi < 4; ++mi)
        #pragma unroll
        for (int r = 0; r < 4; ++r) {
            int m = wm + mi * 16 + ((lane >> 4) << 2) + r;
            int slot = mt * BM + m;
            if (slot < M) {
                int token = lists[e * NMAX + slot];
                float g = gates[e * NMAX + slot];
                #pragma unroll
                for (int ni = 0; ni < 4; ++ni) {
                    int nn = nt * BN + wn + ni * 16 + (lane & 15);
                    float val = g * (acc[mi][ni][r] + b2[(size_t)e * DMODEL + nn]
                                     + x[(size_t)token * DMODEL + nn]);
                    atomicAdd(out + (size_t)token * DMODEL + nn, val);
                }
            }
        }
}

extern "C" void kernel_launch(void* const* d_in, const int* in_sizes, int n_in,
                              void* d_out, int out_size, void* d_ws, size_t ws_size,
                              hipStream_t stream) {
    const float* x      = (const float*)d_in[0];
    const float* gate_w = (const float*)d_in[1];
    const float* ln_g   = (const float*)d_in[2];
    const float* ln_b   = (const float*)d_in[3];
    const float* w1     = (const float*)d_in[4];
    const float* b1     = (const float*)d_in[5];
    const float* w2     = (const float*)d_in[6];
    const float* b2     = (const float*)d_in[7];
    float* out = (float*)d_out;

    char* w = (char*)d_ws;
    int*    cnt    = (int*)w;                       // 8 ints
    int*    offs   = (int*)(w + 32);                // 8 ints
    int*    lists  = (int*)(w + 256);               // E*NMAX ints   = 64 KB
    float*  gates  = (float*)(w + 256 + 65536);     // E*NMAX f32    = 64 KB
    float*  scores = (float*)(w + 256 + 2 * 65536); // N*E f32       = 64 KB
    ushort* norm   = (ushort*)(w + 256 + 3 * 65536);            // N*D bf16 = 4 MB
    ushort* h      = (ushort*)(w + 256 + 3 * 65536 + 4194304);  // 2N*FF bf16 = 33.5 MB

    hipMemsetAsync(d_out, 0, (size_t)out_size * sizeof(float), stream);
    hipMemsetAsync(cnt, 0, 32, stream);

    router_kernel<<<N_TOK, 256, 0, stream>>>(x, gate_w, norm, scores, cnt, lists, gates);
    prep_kernel<<<1, 256, 0, stream>>>(scores, cnt, offs, out + (size_t)N_TOK * DMODEL);
    gemm1_kernel<<<dim3(FFDIM / BN, NMAX / BM, NEXP), 256, 0, stream>>>(
        norm, w1, b1, ln_g, ln_b, cnt, offs, lists, h);
    gemm2_kernel<<<dim3(DMODEL / BN, NMAX / BM, NEXP), 256, 0, stream>>>(
        h, w2, b2, x, cnt, offs, lists, gates, out);
}